// Round 5
// baseline (31.623 us; speedup 1.0000x reference)
//
#include <hip/hip_runtime.h>
#include <math.h>

// AttentionCropLayer: out[b,c,i,j] = images[b,c,w_off+i,h_off+j] * prof[i]*prof[j]
//   tx = clip(locs[b,0]*224, 44, 180); w_off = floor(tx-44)   (same for h via locs[b,1])
// In f32, prof[r] == 1.0f except prof[0]=0.5, prof[1]=prof[87]=1/(1+e^-10).
// Misalignment phase s = h_off & 3 is uniform per block -> aligned float4
// loads at (src - s) + compile-time funnel shift (4 template instantiations).
// R1: 27.45us scalar-cached. R2/3: nt LOADS -36% (L1 bypass on strided scalar).
// R4: vec loads, maskless edges: 27.58us -> not instruction-bound.
// R5: explicit 4-deep MLP (all 8 vec loads issued before any math/store) +
//     nontemporal STORES only. Tests load-latency-limited hypothesis.

#define TLn    44
#define CROP   88
#define INSZ   224
#define NCH    16
#define IPLANE (INSZ * INSZ)      // 50176
#define PLANE  (CROP * CROP)      // 7744
#define OCT    (PLANE / 8)        // 968 8-float chunks (88 % 8 == 0); 11 per row

#define PEDGE 0.9999546021312976f // 1/(1+exp(-10)) in f32

typedef float f32x4 __attribute__((ext_vector_type(4)));

template<int S>
__device__ __forceinline__ void crop_plane(const float* __restrict__ srcA,
                                           float* __restrict__ dst, int t)
{
    // Chunks q_k = t + 256k, k=0..3. 968 = 3*256 + 200 -> k=3 only for t<200.
    const bool has4 = (t < OCT - 3 * 256);

    int qk[4], i0[4], j0[4];
    const float* s4[4];
    #pragma unroll
    for (int k = 0; k < 4; ++k) {
        qk[k] = t + 256 * k;
        i0[k] = qk[k] / 11;                 // i = (8q)/88
        j0[k] = (qk[k] - i0[k] * 11) * 8;   // j in {0,8,...,80}
        s4[k] = srcA + i0[k] * INSZ + j0[k];
    }

    f32x4 v0[4], v1[4];
    float ex[4][3];

    auto ld = [&](int k) {                  // constant k after inlining
        v0[k] = *reinterpret_cast<const f32x4*>(s4[k]);
        v1[k] = *reinterpret_cast<const f32x4*>(s4[k] + 4);
        #pragma unroll
        for (int m = 0; m < S; ++m) ex[k][m] = s4[k][8 + m];
    };
    // Issue ALL loads before any dependent math/store -> 8+ vec loads in flight.
    ld(0); ld(1); ld(2);
    if (has4) ld(3);

    auto emit = [&](int k) {                // constant k after inlining
        float w[8];
        #pragma unroll
        for (int m = 0; m < 8; ++m) {
            const int p = m + S;
            w[m] = (p < 4) ? v0[k][p] : (p < 8) ? v1[k][p - 4] : ex[k][p - 8];
        }
        const int i = i0[k], j = j0[k];
        const float fi = (i == 0) ? 0.5f
                       : ((i == 1) | (i == 87)) ? PEDGE : 1.0f;
        #pragma unroll
        for (int m = 0; m < 8; ++m) w[m] *= fi;
        if (j == 0)  { w[0] *= 0.5f; w[1] *= PEDGE; }
        if (j == 80) { w[7] *= PEDGE; }

        f32x4 a = { w[0], w[1], w[2], w[3] };
        f32x4 c = { w[4], w[5], w[6], w[7] };
        float* d = dst + 8 * qk[k];
        __builtin_nontemporal_store(a, reinterpret_cast<f32x4*>(d));
        __builtin_nontemporal_store(c, reinterpret_cast<f32x4*>(d + 4));
    };
    emit(0); emit(1); emit(2);
    if (has4) emit(3);
}

__global__ __launch_bounds__(256)
void attention_crop_kernel(const float* __restrict__ images,
                           const float* __restrict__ locs,
                           float* __restrict__ out)
{
    const int bc = blockIdx.x;        // b * NCH + c
    const int b  = bc >> 4;
    const int t  = threadIdx.x;

    // Same float32 arithmetic as the reference (values >= 0, trunc == floor).
    const float tx = fminf(fmaxf(locs[2 * b]     * 224.0f, (float)TLn), (float)(INSZ - TLn));
    const float ty = fminf(fmaxf(locs[2 * b + 1] * 224.0f, (float)TLn), (float)(INSZ - TLn));
    const int w_off = (int)floorf(tx - (float)TLn);
    const int h_off = (int)floorf(ty - (float)TLn);

    const int s = h_off & 3;          // uniform per block; s <= h_off (no underflow)
    const float* srcA = images + (size_t)bc * IPLANE + (size_t)w_off * INSZ + (h_off - s);
    float* dst = out + (size_t)bc * PLANE;

    switch (s) {
        case 0: crop_plane<0>(srcA, dst, t); break;
        case 1: crop_plane<1>(srcA, dst, t); break;
        case 2: crop_plane<2>(srcA, dst, t); break;
        default: crop_plane<3>(srcA, dst, t); break;
    }
}

extern "C" void kernel_launch(void* const* d_in, const int* in_sizes, int n_in,
                              void* d_out, int out_size, void* d_ws, size_t ws_size,
                              hipStream_t stream)
{
    const float* images = (const float*)d_in[0];
    const float* locs   = (const float*)d_in[1];
    float*       out    = (float*)d_out;

    const int B = in_sizes[1] / 2;     // 128
    dim3 grid(B * NCH);                // 2048 blocks, one per (b, c) plane
    attention_crop_kernel<<<grid, 256, 0, stream>>>(images, locs, out);
}

// Round 6
// 28.139 us; speedup vs baseline: 1.1238x; 1.1238x over previous
//
#include <hip/hip_runtime.h>
#include <math.h>

// AttentionCropLayer: out[b,c,i,j] = images[b,c,w_off+i,h_off+j] * prof[i]*prof[j]
//   tx = clip(locs[b,0]*224, 44, 180); w_off = floor(tx-44)   (same for h via locs[b,1])
// In f32, prof[r] == 1.0f except prof[0]=0.5, prof[1]=prof[87]=1/(1+e^-10).
// Misalignment phase s = h_off & 3 is uniform per block -> aligned float4
// loads at (src - s) + compile-time funnel shift (4 template instantiations).
// History: R1 27.45us (scalar cached loads). R2/3 nt loads: -36% (L1 bypass on
// strided scalar -> 8x L2 refetch). R4 27.58us (vec loads, maskless edges) ->
// not instruction-bound. R5 31.62us (batched loads + NT STORES) -> nt stores
// slow on gfx950. R6: R5 structure, NORMAL stores — isolates the 4-deep MLP
// (8 vec loads in flight before any dependent math/store).

#define TLn    44
#define CROP   88
#define INSZ   224
#define NCH    16
#define IPLANE (INSZ * INSZ)      // 50176
#define PLANE  (CROP * CROP)      // 7744
#define OCT    (PLANE / 8)        // 968 8-float chunks (88 % 8 == 0); 11 per row

#define PEDGE 0.9999546021312976f // 1/(1+exp(-10)) in f32

typedef float f32x4 __attribute__((ext_vector_type(4)));

template<int S>
__device__ __forceinline__ void crop_plane(const float* __restrict__ srcA,
                                           float* __restrict__ dst, int t)
{
    // Chunks q_k = t + 256k, k=0..3. 968 = 3*256 + 200 -> k=3 only for t<200.
    const bool has4 = (t < OCT - 3 * 256);

    int qk[4], i0[4], j0[4];
    const float* s4[4];
    #pragma unroll
    for (int k = 0; k < 4; ++k) {
        qk[k] = t + 256 * k;
        i0[k] = qk[k] / 11;                 // row index (11 chunks per row)
        j0[k] = (qk[k] - i0[k] * 11) * 8;   // col in {0,8,...,80}
        s4[k] = srcA + i0[k] * INSZ + j0[k];
    }

    f32x4 v0[4], v1[4];
    float ex[4][3];

    auto ld = [&](int k) {                  // constant k after inlining
        v0[k] = *reinterpret_cast<const f32x4*>(s4[k]);
        v1[k] = *reinterpret_cast<const f32x4*>(s4[k] + 4);
        #pragma unroll
        for (int m = 0; m < S; ++m) ex[k][m] = s4[k][8 + m];
    };
    // Issue ALL loads before any dependent math/store -> 8+ vec loads in flight.
    ld(0); ld(1); ld(2);
    if (has4) ld(3);

    auto emit = [&](int k) {                // constant k after inlining
        float w[8];
        #pragma unroll
        for (int m = 0; m < 8; ++m) {
            const int p = m + S;
            w[m] = (p < 4) ? v0[k][p] : (p < 8) ? v1[k][p - 4] : ex[k][p - 8];
        }
        const int i = i0[k], j = j0[k];
        const float fi = (i == 0) ? 0.5f
                       : ((i == 1) | (i == 87)) ? PEDGE : 1.0f;
        #pragma unroll
        for (int m = 0; m < 8; ++m) w[m] *= fi;
        if (j == 0)  { w[0] *= 0.5f; w[1] *= PEDGE; }
        if (j == 80) { w[7] *= PEDGE; }

        f32x4 a = { w[0], w[1], w[2], w[3] };
        f32x4 c = { w[4], w[5], w[6], w[7] };
        float* d = dst + 8 * qk[k];
        *reinterpret_cast<f32x4*>(d)     = a;   // normal cached stores
        *reinterpret_cast<f32x4*>(d + 4) = c;
    };
    emit(0); emit(1); emit(2);
    if (has4) emit(3);
}

__global__ __launch_bounds__(256)
void attention_crop_kernel(const float* __restrict__ images,
                           const float* __restrict__ locs,
                           float* __restrict__ out)
{
    const int bc = blockIdx.x;        // b * NCH + c
    const int b  = bc >> 4;
    const int t  = threadIdx.x;

    // Same float32 arithmetic as the reference (values >= 0, trunc == floor).
    const float tx = fminf(fmaxf(locs[2 * b]     * 224.0f, (float)TLn), (float)(INSZ - TLn));
    const float ty = fminf(fmaxf(locs[2 * b + 1] * 224.0f, (float)TLn), (float)(INSZ - TLn));
    const int w_off = (int)floorf(tx - (float)TLn);
    const int h_off = (int)floorf(ty - (float)TLn);

    const int s = h_off & 3;          // uniform per block; s <= h_off (no underflow)
    const float* srcA = images + (size_t)bc * IPLANE + (size_t)w_off * INSZ + (h_off - s);
    float* dst = out + (size_t)bc * PLANE;

    switch (s) {
        case 0: crop_plane<0>(srcA, dst, t); break;
        case 1: crop_plane<1>(srcA, dst, t); break;
        case 2: crop_plane<2>(srcA, dst, t); break;
        default: crop_plane<3>(srcA, dst, t); break;
    }
}

extern "C" void kernel_launch(void* const* d_in, const int* in_sizes, int n_in,
                              void* d_out, int out_size, void* d_ws, size_t ws_size,
                              hipStream_t stream)
{
    const float* images = (const float*)d_in[0];
    const float* locs   = (const float*)d_in[1];
    float*       out    = (float*)d_out;

    const int B = in_sizes[1] / 2;     // 128
    dim3 grid(B * NCH);                // 2048 blocks, one per (b, c) plane
    attention_crop_kernel<<<grid, 256, 0, stream>>>(images, locs, out);
}

// Round 7
// 27.470 us; speedup vs baseline: 1.1512x; 1.0244x over previous
//
#include <hip/hip_runtime.h>
#include <math.h>

// AttentionCropLayer: out[b,c,i,j] = images[b,c,w_off+i,h_off+j] * prof[i]*prof[j]
//   tx = clip(locs[b,0]*224, 44, 180); w_off = floor(tx-44)   (same for h via locs[b,1])
//   prof[r] = sigmoid(10*r) - sigmoid(10*(r-88))
// Shapes: images [128,16,224,224] f32, locs [128,2] f32, out [128,16,88,88] f32.
//
// Session summary (all on gfx950, MI355X):
//   R1 27.45us  scalar cached loads + LDS mask            <- champion (this file)
//   R2/3        nontemporal LOADS: -36% (L1 bypass on 32B-strided scalar loads
//               -> each line re-fetched from L2 up to 8x). Avoid.
//   R4 27.58us  aligned float4 loads (uniform h_off&3 phase, funnel shift),
//               maskless edge multiplies -> NOT instruction-bound.
//   R5 31.62us  nontemporal STORES: -15%. Avoid nt hints entirely here.
//   R6 28.14us  4-deep batched loads (8 vec loads in flight) -> MLP null.
// Conclusion: memory-system floor ~27.5us. Physical traffic ~140-150 MB
// (63.4 MB useful read + intrinsic 64B-sector overfetch on unaligned 352B
// rows at 896B stride, + 63.4 MB coalesced write) = 5.2-5.4 TB/s, 83-87% of
// the 6.3 TB/s copy ceiling. No data reuse exists -> no tiling lever. ROOFLINE.

#define TLn   44
#define CROP  88
#define INSZ  224
#define NCH   16
#define PLANE (CROP * CROP)     // 7744
#define QPLANE (PLANE / 4)      // 1936 float4 per plane

__global__ __launch_bounds__(256)
void attention_crop_kernel(const float* __restrict__ images,
                           const float* __restrict__ locs,
                           float* __restrict__ out)
{
    __shared__ float prof[CROP];
    __shared__ int   offs[2];

    const int bc = blockIdx.x;        // b * NCH + c
    const int b  = bc >> 4;
    const int t  = threadIdx.x;

    // Mask profile (identical for all blocks; 88 expf's per block is negligible).
    if (t < CROP) {
        float r  = (float)t;
        float s1 = 1.0f / (1.0f + expf(-10.0f * r));
        float s2 = 1.0f / (1.0f + expf(-10.0f * (r - (float)CROP)));
        prof[t] = s1 - s2;
    }
    // Per-batch crop offsets — same float32 arithmetic as the reference.
    if (t == 0) {
        float tx = fminf(fmaxf(locs[2 * b]     * 224.0f, (float)TLn), (float)(INSZ - TLn));
        float ty = fminf(fmaxf(locs[2 * b + 1] * 224.0f, (float)TLn), (float)(INSZ - TLn));
        offs[0] = (int)floorf(tx - (float)TLn);   // value in [0,136], trunc == floor
        offs[1] = (int)floorf(ty - (float)TLn);
    }
    __syncthreads();

    const int w_off = offs[0];
    const int h_off = offs[1];

    const float* __restrict__ src =
        images + ((size_t)bc * INSZ + (size_t)w_off) * INSZ + h_off;
    float* __restrict__ dst = out + (size_t)bc * PLANE;

    // Each thread: 4 consecutive output floats per iteration (never crosses a
    // crop row since 88 % 4 == 0). Input is only 4B-aligned (h_off arbitrary)
    // -> scalar loads; output plane base is 16B-aligned -> float4 store.
    for (int q = t; q < QPLANE; q += 256) {
        const int e = q * 4;
        const int i = e / CROP;
        const int j = e - i * CROP;

        const float* __restrict__ s = src + (size_t)i * INSZ + j;
        float4 v;
        v.x = s[0];
        v.y = s[1];
        v.z = s[2];
        v.w = s[3];

        const float pi = prof[i];
        v.x *= pi * prof[j];
        v.y *= pi * prof[j + 1];
        v.z *= pi * prof[j + 2];
        v.w *= pi * prof[j + 3];

        *reinterpret_cast<float4*>(dst + e) = v;
    }
}

extern "C" void kernel_launch(void* const* d_in, const int* in_sizes, int n_in,
                              void* d_out, int out_size, void* d_ws, size_t ws_size,
                              hipStream_t stream)
{
    const float* images = (const float*)d_in[0];
    const float* locs   = (const float*)d_in[1];
    float*       out    = (float*)d_out;

    const int B = in_sizes[1] / 2;     // 128
    dim3 grid(B * NCH);                // 2048 blocks, one per (b, c) plane
    attention_crop_kernel<<<grid, 256, 0, stream>>>(images, locs, out);
}